// Round 1
// baseline (148.693 us; speedup 1.0000x reference)
//
#include <hip/hip_runtime.h>

// 2-layer tanh RNN, INP=6, HID=8, B=4096, T=512, + linear head to 1.
// Decomposition: 8 lanes per batch element; lane j owns hidden unit j of
// both layers. Weights live in per-lane VGPRs (rows j). Cross-lane h
// broadcast via ds_swizzle BitMode (group-of-8 broadcast), head reduction
// via XOR butterfly. One fused kernel, no LDS storage, no barriers.

#define INP 6
#define HID 8
#define BATCH 4096
#define TT 512

// broadcast lane ((lane & 0x18) | K) within each 32-lane half (groups of 8)
template<int K>
__device__ __forceinline__ float b8(float v) {
    return __int_as_float(__builtin_amdgcn_ds_swizzle(__float_as_int(v), (K << 5) | 0x18));
}
// xor-lane swizzle within group (and=0x1F keeps all bits, xor=M)
template<int M>
__device__ __forceinline__ float x8(float v) {
    return __int_as_float(__builtin_amdgcn_ds_swizzle(__float_as_int(v), (M << 10) | 0x1F));
}

// sum w[k] * h_broadcast(k), two chains for ILP
__device__ __forceinline__ float dot8(const float* w, float h) {
    float a = w[0] * b8<0>(h);
    float b = w[1] * b8<1>(h);
    a = fmaf(w[2], b8<2>(h), a);
    b = fmaf(w[3], b8<3>(h), b);
    a = fmaf(w[4], b8<4>(h), a);
    b = fmaf(w[5], b8<5>(h), b);
    a = fmaf(w[6], b8<6>(h), a);
    b = fmaf(w[7], b8<7>(h), b);
    return a + b;
}

// full sum across the 8-lane group (all lanes end with the total)
__device__ __forceinline__ float xorsum8(float v) {
    v += x8<1>(v);
    v += x8<2>(v);
    v += x8<4>(v);
    return v;
}

// tanh(z) = 1 - 2/(e^{2z}+1); v_exp + v_rcp, exact saturation at +/-inf
__device__ __forceinline__ float ftanh(float z) {
    float e = __expf(2.0f * z);
    return 1.0f - 2.0f * __builtin_amdgcn_rcpf(e + 1.0f);
}

__global__ __launch_bounds__(128) void rnn_fused(
    const float* __restrict__ x,
    const float* __restrict__ Wih0, const float* __restrict__ Whh0,
    const float* __restrict__ bih0, const float* __restrict__ bhh0,
    const float* __restrict__ Wih1, const float* __restrict__ Whh1,
    const float* __restrict__ bih1, const float* __restrict__ bhh1,
    const float* __restrict__ Wout, const float* __restrict__ bout,
    float* __restrict__ out)
{
    const int gtid = blockIdx.x * blockDim.x + threadIdx.x;
    const int b = gtid >> 3;   // batch element
    const int j = gtid & 7;    // hidden unit owned by this lane

    // per-lane weight rows (static indexing after unroll -> stay in VGPRs)
    float wih0[INP], whh0[HID], wih1[HID], whh1[HID];
#pragma unroll
    for (int d = 0; d < INP; d++) wih0[d] = Wih0[j * INP + d];
#pragma unroll
    for (int k = 0; k < HID; k++) {
        whh0[k] = Whh0[j * HID + k];
        wih1[k] = Wih1[j * HID + k];
        whh1[k] = Whh1[j * HID + k];
    }
    const float b0 = bih0[j] + bhh0[j];
    const float b1 = bih1[j] + bhh1[j];
    const float wo = Wout[j];
    const float bo = bout[0];

    const float* xb = x + (size_t)b * TT * INP;
    float* ob = out + (size_t)b * TT;

    float h1 = 0.0f, h2 = 0.0f;

    for (int t0 = 0; t0 < TT; t0 += 8) {
        // stage 8 timesteps of x (48 floats, 8B-aligned float2 loads).
        // all 8 lanes of a group load the same 48B window -> L1 broadcast.
        float xs[48];
#pragma unroll
        for (int u = 0; u < 24; u++) {
            float2 v = *reinterpret_cast<const float2*>(xb + t0 * INP + u * 2);
            xs[u * 2] = v.x;
            xs[u * 2 + 1] = v.y;
        }

        float oreg = 0.0f;
#pragma unroll
        for (int s = 0; s < 8; s++) {
            // layer 0: input projection + recurrent matmul + tanh
            float a = b0;
#pragma unroll
            for (int d = 0; d < INP; d++) a = fmaf(wih0[d], xs[s * INP + d], a);
            a += dot8(whh0, h1);
            float h1n = ftanh(a);

            // layer 1: projection of h1 + recurrent matmul + tanh
            float a2 = b1 + dot8(wih1, h1n) + dot8(whh1, h2);
            h2 = ftanh(a2);
            h1 = h1n;

            // head: sum_j wo[j]*h2[j] + b_out; lane s of the group keeps t0+s
            float o = xorsum8(wo * h2) + bo;
            oreg = (j == s) ? o : oreg;
        }
        // coalesced: lane j stores timestep t0+j of its batch element
        ob[t0 + j] = oreg;
    }
}

extern "C" void kernel_launch(void* const* d_in, const int* in_sizes, int n_in,
                              void* d_out, int out_size, void* d_ws, size_t ws_size,
                              hipStream_t stream) {
    const float* x    = (const float*)d_in[0];
    const float* Wih0 = (const float*)d_in[1];
    const float* Whh0 = (const float*)d_in[2];
    const float* bih0 = (const float*)d_in[3];
    const float* bhh0 = (const float*)d_in[4];
    const float* Wih1 = (const float*)d_in[5];
    const float* Whh1 = (const float*)d_in[6];
    const float* bih1 = (const float*)d_in[7];
    const float* bhh1 = (const float*)d_in[8];
    const float* Wout = (const float*)d_in[9];
    const float* bout = (const float*)d_in[10];
    float* out = (float*)d_out;

    const int threads = BATCH * HID;   // 32768: 8 lanes per batch element
    const int block = 128;             // 2 waves/CU across 256 CUs; keeps LDS pipe unsaturated
    const int grid = threads / block;  // 256

    rnn_fused<<<grid, block, 0, stream>>>(x, Wih0, Whh0, bih0, bhh0,
                                          Wih1, Whh1, bih1, bhh1,
                                          Wout, bout, out);
}

// Round 2
// 84.130 us; speedup vs baseline: 1.7674x; 1.7674x over previous
//
#include <hip/hip_runtime.h>

// 2-layer tanh RNN, INP=6, HID=8, B=4096, T=512, + linear head to 1.
// 8 lanes per batch element; lane j owns hidden unit j of both layers.
// ALL cross-lane movement via DPP (VALU pipe, ~2cyc) instead of ds_swizzle
// (LDS round-trip ~120cyc): recurrent dot products are XOR-gather butterflies
// with per-lane weights pre-permuted so slot M holds W[j][j^M].
// x is double-buffered in registers (asm-pinned so the compiler can't sink
// the loads back into the recurrence chain).

#define INP 6
#define HID 8
#define BATCH 4096
#define TT 512

// DPP controls
#define DPP_XOR1 0xB1   // quad_perm(1,0,3,2): lane ^ 1
#define DPP_XOR2 0x4E   // quad_perm(2,3,0,1): lane ^ 2
#define DPP_XOR3 0x1B   // quad_perm(3,2,1,0): lane ^ 3
#define DPP_HMIR 0x141  // row_half_mirror:    lane ^ 7 (within 8)

template<int CTRL>
__device__ __forceinline__ float fdpp(float v) {
    return __int_as_float(__builtin_amdgcn_update_dpp(
        0, __float_as_int(v), CTRL, 0xF, 0xF, true));
}

// dot over the 8-lane group: w is pre-permuted, w[M] = W[j][j^M].
// gathers: M=1..3 direct quad_perm; M=4..6 derived from g7 = h[j^7].
__device__ __forceinline__ float dot8x(const float* w, float h) {
    float g7 = fdpp<DPP_HMIR>(h);
    float a = w[0] * h;
    float b = w[1] * fdpp<DPP_XOR1>(h);
    a = fmaf(w[2], fdpp<DPP_XOR2>(h), a);
    b = fmaf(w[3], fdpp<DPP_XOR3>(h), b);
    a = fmaf(w[4], fdpp<DPP_XOR3>(g7), a);   // (j^7)^3 = j^4
    b = fmaf(w[5], fdpp<DPP_XOR2>(g7), b);   // j^5
    a = fmaf(w[6], fdpp<DPP_XOR1>(g7), a);   // j^6
    b = fmaf(w[7], g7, b);                   // j^7
    return a + b;
}

// tanh(z) = 1 - 2/(exp2(z*2/ln2)+1); exact saturation at +/-inf
__device__ __forceinline__ float ftanh(float z) {
    float e = __builtin_amdgcn_exp2f(z * 2.885390082f);
    return 1.0f - 2.0f * __builtin_amdgcn_rcpf(e + 1.0f);
}

__global__ __launch_bounds__(128) void rnn_fused(
    const float* __restrict__ x,
    const float* __restrict__ Wih0, const float* __restrict__ Whh0,
    const float* __restrict__ bih0, const float* __restrict__ bhh0,
    const float* __restrict__ Wih1, const float* __restrict__ Whh1,
    const float* __restrict__ bih1, const float* __restrict__ bhh1,
    const float* __restrict__ Wout, const float* __restrict__ bout,
    float* __restrict__ out)
{
    const int gtid = blockIdx.x * blockDim.x + threadIdx.x;
    const int b = gtid >> 3;   // batch element
    const int j = gtid & 7;    // hidden unit owned by this lane

    // per-lane weight rows; recurrent/projection rows stored XOR-permuted
    float wih0[INP], whh0p[HID], wih1p[HID], whh1p[HID];
#pragma unroll
    for (int d = 0; d < INP; d++) wih0[d] = Wih0[j * INP + d];
#pragma unroll
    for (int M = 0; M < HID; M++) {
        whh0p[M] = Whh0[j * HID + (j ^ M)];
        wih1p[M] = Wih1[j * HID + (j ^ M)];
        whh1p[M] = Whh1[j * HID + (j ^ M)];
    }
    const float b0 = bih0[j] + bhh0[j];
    const float b1 = bih1[j] + bhh1[j];
    const float wo = Wout[j];
    const float bo = bout[0];

    const float* xb = x + (size_t)b * TT * INP;
    float* ob = out + (size_t)b * TT;

    float h1 = 0.0f, h2 = 0.0f;
    float xsA[48], xsB[48];   // 8 timesteps of x, double-buffered

    auto loadblk = [&](float (&xs)[48], int t0) {
#pragma unroll
        for (int u = 0; u < 24; u++) {
            float2 v = *reinterpret_cast<const float2*>(xb + t0 * INP + u * 2);
            xs[2 * u] = v.x;
            xs[2 * u + 1] = v.y;
        }
        // pin staged values in VGPRs so the loads can't be sunk into the chain
#pragma unroll
        for (int u = 0; u < 48; u++) asm volatile("" : "+v"(xs[u]));
    };

    auto compute8 = [&](const float (&xs)[48], int t0) {
        float oreg = 0.0f;
#pragma unroll
        for (int s = 0; s < 8; s++) {
            // layer 0
            float a = b0;
#pragma unroll
            for (int d = 0; d < INP; d++) a = fmaf(wih0[d], xs[s * INP + d], a);
            a += dot8x(whh0p, h1);
            float h1n = ftanh(a);
            // layer 1
            float a2 = b1 + dot8x(wih1p, h1n) + dot8x(whh1p, h2);
            h2 = ftanh(a2);
            h1 = h1n;
            // head: group sum of wo*h2; lane s keeps timestep t0+s
            float o = wo * h2;
            o += fdpp<DPP_XOR1>(o);
            o += fdpp<DPP_XOR2>(o);
            o += fdpp<DPP_HMIR>(o);   // quad-uniform by now: xor7 fetches other quad
            oreg = (j == s) ? o : oreg;
        }
        ob[t0 + j] = oreg + bo;   // coalesced 8-wide store per group
    };

    loadblk(xsA, 0);
    for (int t0 = 0; t0 < TT; t0 += 16) {
        loadblk(xsB, t0 + 8);
        compute8(xsA, t0);
        if (t0 + 16 < TT) loadblk(xsA, t0 + 16);
        compute8(xsB, t0 + 8);
    }
}

extern "C" void kernel_launch(void* const* d_in, const int* in_sizes, int n_in,
                              void* d_out, int out_size, void* d_ws, size_t ws_size,
                              hipStream_t stream) {
    const float* x    = (const float*)d_in[0];
    const float* Wih0 = (const float*)d_in[1];
    const float* Whh0 = (const float*)d_in[2];
    const float* bih0 = (const float*)d_in[3];
    const float* bhh0 = (const float*)d_in[4];
    const float* Wih1 = (const float*)d_in[5];
    const float* Whh1 = (const float*)d_in[6];
    const float* bih1 = (const float*)d_in[7];
    const float* bhh1 = (const float*)d_in[8];
    const float* Wout = (const float*)d_in[9];
    const float* bout = (const float*)d_in[10];
    float* out = (float*)d_out;

    const int threads = BATCH * HID;   // 32768: 8 lanes per batch element
    const int block = 128;
    const int grid = threads / block;  // 256

    rnn_fused<<<grid, block, 0, stream>>>(x, Wih0, Whh0, bih0, bhh0,
                                          Wih1, Whh1, bih1, bhh1,
                                          Wout, bout, out);
}